// Round 1
// baseline (209.204 us; speedup 1.0000x reference)
//
#include <hip/hip_runtime.h>
#include <cstdint>

// CamPoseNet: bit-faithful JAX threefry replication (validated rounds 1-4).
// Round 6: occupancy fix. Model from R4/R5 counters: per-wave tail is an
// additive ~16 iters regardless of rows/lane (R4: 12.4+16, R5: 50+16), so
// GRID=512's 8-rows/lane tail amortization bought little, while dropping to
// 2 waves/SIMD capped VALUBusy at ~49% (dep-chain latency 4cyc vs 2cyc
// issue + 1/4-rate trans pipe). GRID=1024 -> 4 blocks/CU, 4 waves/SIMD:
// issued-cycles 189M->235M (worse tail ratio) but busy 0.50->~0.90.
// Predicted ~103us vs measured 154us dispatch.
//  - wave 0 of each block produces the 96-entry split()-chain into LDS behind
//    an LDS watermark; waves 1-3 consume immediately (producer ~5x faster
//    than consumption rate).
//  - hot loop: chain[t+1] prefetched at iteration top; chain[0] cached in
//    registers for accepts; NEXT row+Z pre-grabbed at accept (queue atomic
//    and Z load get iterations of slack); E^T epilogue deferred to a
//    coalesced per-block pass after the loop; select-based erfinv branches.
// All float ops on the accept-decision path use __f*_rn intrinsics (no FMA
// contraction) - matches XLA:CPU strict mul/add. Do not alter any arithmetic.

#define DEVI __device__ __forceinline__
#define MAXT 96
#define GRID 1024
#define NT 256

DEVI uint32_t rotl32(uint32_t v, int s) { return (v << s) | (v >> (32 - s)); }

// Threefry-2x32, 20 rounds (jax._src.prng.threefry2x32).
DEVI void tf2x32(uint32_t k0, uint32_t k1, uint32_t x0, uint32_t x1,
                 uint32_t& o0, uint32_t& o1) {
  const uint32_t kx = k0 ^ k1 ^ 0x1BD11BDAu;
  x0 += k0; x1 += k1;
#define TFR(r) x0 += x1; x1 = rotl32(x1, (r)); x1 ^= x0;
  TFR(13) TFR(15) TFR(26) TFR(6)
  x0 += k1; x1 += kx + 1u;
  TFR(17) TFR(29) TFR(16) TFR(24)
  x0 += kx; x1 += k0 + 2u;
  TFR(13) TFR(15) TFR(26) TFR(6)
  x0 += k0; x1 += k1 + 3u;
  TFR(17) TFR(29) TFR(16) TFR(24)
  x0 += k1; x1 += kx + 4u;
  TFR(13) TFR(15) TFR(26) TFR(6)
  x0 += kx; x1 += k0 + 5u;
#undef TFR
  o0 = x0; o1 = x1;
}

// XLA:CPU Cephes-style f32 log, strict mul/add. x > 0, normal.
DEVI float xla_logf_pos(float xf) {
  uint32_t bits = __float_as_uint(xf);
  float e = (float)((int)(bits >> 23) - 126);
  float m = __uint_as_float((bits & 0x007fffffu) | 0x3f000000u);  // [0.5,1)
  if (m < 0.70710678118654752440f) {
    e = __fsub_rn(e, 1.0f);
    m = __fadd_rn(__fsub_rn(m, 1.0f), m);
  } else {
    m = __fsub_rn(m, 1.0f);
  }
  float z = __fmul_rn(m, m);
  float y = 7.0376836292e-2f;
  y = __fadd_rn(__fmul_rn(y, m), -1.1514610310e-1f);
  y = __fadd_rn(__fmul_rn(y, m),  1.1676998740e-1f);
  y = __fadd_rn(__fmul_rn(y, m), -1.2420140846e-1f);
  y = __fadd_rn(__fmul_rn(y, m),  1.4249322787e-1f);
  y = __fadd_rn(__fmul_rn(y, m), -1.6668057665e-1f);
  y = __fadd_rn(__fmul_rn(y, m),  2.0000714765e-1f);
  y = __fadd_rn(__fmul_rn(y, m), -2.4999993993e-1f);
  y = __fadd_rn(__fmul_rn(y, m),  3.3333331174e-1f);
  y = __fmul_rn(y, m);
  y = __fmul_rn(y, z);
  y = __fadd_rn(y, __fmul_rn(e, -2.12194440e-4f));
  y = __fsub_rn(y, __fmul_rn(z, 0.5f));
  float r = __fadd_rn(m, y);
  r = __fadd_rn(r, __fmul_rn(e, 0.693359375f));
  return r;
}

// XLA EmitLog1p, select form (bit-identical per lane to the branchy version)
DEVI float xla_log1pf(float v) {
  float small = __fmul_rn(__fadd_rn(__fmul_rn(-0.5f, v), 1.0f), v);
  float big = xla_logf_pos(__fadd_rn(v, 1.0f));
  return (fabsf(v) < 1e-4f) ? small : big;
}

// XLA ErfInv32, coefficient-select form: identical op sequence per lane as
// the taken branch -> bit-exact, but no dual-path exec-mask waste.
DEVI float xla_erfinvf(float x) {
  float w = -xla_log1pf(-__fmul_rn(x, x));
  bool c = (w < 5.0f);
  float qc = __fsub_rn(w, 2.5f);
  float qr = __fsub_rn(sqrtf(w), 3.0f);
  float q = c ? qc : qr;
  float p =                          c ? 2.81022636e-08f : -0.000200214257f;
  p = __fadd_rn(__fmul_rn(p, q), c ?  3.43273939e-07f :  0.000100950558f);
  p = __fadd_rn(__fmul_rn(p, q), c ? -3.5233877e-06f  :  0.00134934322f);
  p = __fadd_rn(__fmul_rn(p, q), c ? -4.39150654e-06f : -0.00367342844f);
  p = __fadd_rn(__fmul_rn(p, q), c ?  0.00021858087f  :  0.00573950773f);
  p = __fadd_rn(__fmul_rn(p, q), c ? -0.00125372503f  : -0.0076224613f);
  p = __fadd_rn(__fmul_rn(p, q), c ? -0.00417768164f  :  0.00943887047f);
  p = __fadd_rn(__fmul_rn(p, q), c ?  0.246640727f    :  1.00167406f);
  p = __fadd_rn(__fmul_rn(p, q), c ?  1.50140941f     :  2.83297682f);
  return __fmul_rn(p, x);
}

DEVI float u01_from_bits(uint32_t bits) {
  return __fsub_rn(__uint_as_float(0x3f800000u | (bits >> 9)), 1.0f);
}

// ---------------------------------------------------------------------------
__global__ __launch_bounds__(256) void campose_kernel(
    const float* __restrict__ q, const float* __restrict__ Z,
    float* __restrict__ out, const int* __restrict__ seedp, int N, int C) {
  __shared__ uint4 chain[MAXT + 1];
  __shared__ uint32_t next_row;
  __shared__ uint32_t wm;   // watermark: # of published chain entries

  const int tid = threadIdx.x;
  const int rbeg = blockIdx.x * C;
  const int rend = min(N, rbeg + C);
  if (tid == 0) { next_row = (uint32_t)(rbeg + 192); wm = 0u; }
  __syncthreads();

  const int wave = tid >> 6;
  if (wave == 0) {
    // Producer: lanes 0-2 of wave 0 walk the split() chain; publish each
    // entry with a release watermark. Other waves consume concurrently.
    int lane = tid & 63;
    uint32_t ka = 0u, kb = (uint32_t)seedp[0];
    uint32_t x1i = (lane == 2) ? 0u : (uint32_t)(lane + 1);
    for (int t = 0; t < MAXT; ++t) {
      uint32_t o0 = 0u, o1 = 0u;
      if (lane < 3) tf2x32(ka, kb, 0u, x1i, o0, o1);
      uint32_t s1a = __shfl(o0, 0, 64), s1b = __shfl(o1, 0, 64);
      uint32_t s2a = __shfl(o0, 1, 64), s2b = __shfl(o1, 1, 64);
      if (lane == 0) chain[t] = make_uint4(s1a, s1b, s2a, s2b);
      ka = __shfl(o0, 2, 64); kb = __shfl(o1, 2, 64);
      __threadfence_block();
      if (lane == 0) *(volatile uint32_t*)&wm = (uint32_t)(t + 1);
    }
    if (lane == 0) chain[MAXT] = make_uint4(0u, 0u, 0u, 0u);  // prefetch pad
    __threadfence_block();
    if (lane == 0) *(volatile uint32_t*)&wm = (uint32_t)(MAXT + 1);
  }

  const float sgi0 = __fadd_rn(1.0f, __fmul_rn(2.0f, 1e-6f));
  const float sig0 = sqrtf(__fdiv_rn(1.0f, sgi0));

  // --- per-lane row state: current row r + pre-grabbed next row rn ---
  int r, rn;
  if (wave == 0) {
    r  = (int)atomicAdd(&next_row, 1u);   // producer wave joins late; queue
    rn = (int)atomicAdd(&next_row, 1u);   // auto-balances
  } else {
    r  = rbeg + (tid - 64);               // static first 192 rows
    rn = (int)atomicAdd(&next_row, 1u);
  }
  bool have = (r < rend);
  float Zc0 = 0, Zc1 = 0, Zc2 = 0, Zn0 = 0, Zn1 = 0, Zn2 = 0;
  if (have)      { Zc0 = Z[r * 3 + 0];  Zc1 = Z[r * 3 + 1];  Zc2 = Z[r * 3 + 2]; }
  if (rn < rend) { Zn0 = Z[rn * 3 + 0]; Zn1 = Z[rn * 3 + 1]; Zn2 = Z[rn * 3 + 2]; }

  // wait for chain[0]; cache it (reused at every accept)
  uint32_t wml = *(volatile uint32_t*)&wm;
  while (wml < 1u) wml = *(volatile uint32_t*)&wm;
  __threadfence_block();
  const uint4 ck0 = chain[0];
  uint4 ck = ck0;
  bool chain_all = (wml >= (uint32_t)(MAXT + 1));
  int t = 0;

  while (__ballot(have)) {
    if (have) {
      // prefetch next iteration's subkeys NOW (full iteration of slack)
      if (!chain_all) {
        uint32_t need = (uint32_t)(t + 2);
        uint32_t w_ = *(volatile uint32_t*)&wm;
        while (w_ < need) w_ = *(volatile uint32_t*)&wm;
        __threadfence_block();
        chain_all = (w_ >= (uint32_t)(MAXT + 1));
      }
      uint4 ckn = chain[t + 1];

      const uint32_t base = ((uint32_t)r) * 4u;

      // 4 normal variates (key = s1 subkey, counters base..base+3).
      float nv[4];
#pragma unroll
      for (int j = 0; j < 4; ++j) {
        uint32_t o0, o1;
        tf2x32(ck.x, ck.y, 0u, base + (uint32_t)j, o0, o1);
        float u = u01_from_bits(o0 ^ o1);
        float xin = __fadd_rn(__fmul_rn(u, 2.0f), -0.99999994f);
        xin = fmaxf(-0.99999994f, xin);
        nv[j] = __fmul_rn(1.41421356237309504880f, xla_erfinvf(xin));
      }

      // uniform draw (key = s2 subkey, counter r)
      uint32_t uo0, uo1;
      tf2x32(ck.z, ck.w, 0u, (uint32_t)r, uo0, uo1);
      float uu = u01_from_bits(uo0 ^ uo1);

      // row-dependent constants (Z prefetched a full row-lifetime ago)
      float lam1 = -Zc0, lam2 = -Zc1, lam3 = -Zc2;
      float sgi1 = __fadd_rn(1.0f, __fmul_rn(2.0f, lam1));
      float sgi2 = __fadd_rn(1.0f, __fmul_rn(2.0f, lam2));
      float sgi3 = __fadd_rn(1.0f, __fmul_rn(2.0f, lam3));
      float sig1 = sqrtf(__fdiv_rn(1.0f, sgi1));
      float sig2 = sqrtf(__fdiv_rn(1.0f, sgi2));
      float sig3 = sqrtf(__fdiv_rn(1.0f, sgi3));

      float y0 = __fmul_rn(nv[0], sig0);
      float y1 = __fmul_rn(nv[1], sig1);
      float y2v = __fmul_rn(nv[2], sig2);
      float y3 = __fmul_rn(nv[3], sig3);

      // normalize (sequential reduce order)
      float n2 = __fmul_rn(y0, y0);
      n2 = __fadd_rn(n2, __fmul_rn(y1, y1));
      n2 = __fadd_rn(n2, __fmul_rn(y2v, y2v));
      n2 = __fadd_rn(n2, __fmul_rn(y3, y3));
      float nr = sqrtf(n2);
      y0 = __fdiv_rn(y0, nr); y1 = __fdiv_rn(y1, nr);
      y2v = __fdiv_rn(y2v, nr); y3 = __fdiv_rn(y3, nr);

      float s0q = __fmul_rn(y0, y0), s1q = __fmul_rn(y1, y1);
      float s2q = __fmul_rn(y2v, y2v), s3q = __fmul_rn(y3, y3);

      float s1 = __fmul_rn(s0q, 1e-6f);
      s1 = __fadd_rn(s1, __fmul_rn(s1q, lam1));
      s1 = __fadd_rn(s1, __fmul_rn(s2q, lam2));
      s1 = __fadd_rn(s1, __fmul_rn(s3q, lam3));

      float s2 = __fmul_rn(s0q, sgi0);
      s2 = __fadd_rn(s2, __fmul_rn(s1q, sgi1));
      s2 = __fadd_rn(s2, __fmul_rn(s2q, sgi2));
      s2 = __fadd_rn(s2, __fmul_rn(s3q, sgi3));

      float lr = __fsub_rn(-s1, 2.7725887298583984f);  // 2*f32(ln 4)
      lr = __fadd_rn(lr, 1.5f);
      lr = __fadd_rn(lr, __fmul_rn(2.0f, xla_logf_pos(s2)));

      float lu = (uu > 0.0f) ? xla_logf_pos(uu) : -__builtin_inff();

      ++t;
      if ((lu < lr) || (t >= MAXT)) {
        // lean accept path: store y; E^T deferred to pass 2
        *reinterpret_cast<float4*>(out + (size_t)r * 4) =
            make_float4(y0, y1, y2v, y3);
        r = rn; Zc0 = Zn0; Zc1 = Zn1; Zc2 = Zn2;
        t = 0;
        ck = ck0;
        have = (r < rend);
        rn = (int)atomicAdd(&next_row, 1u);   // pre-grab: ~4.5 iters of slack
        if (rn < rend) {
          Zn0 = Z[rn * 3 + 0]; Zn1 = Z[rn * 3 + 1]; Zn2 = Z[rn * 3 + 2];
        }
      } else {
        ck = ckn;
      }
    }
  }

  // --- pass 2: apply E^T over this block's chunk (coalesced) ---
  __syncthreads();   // all y-stores visible block-wide
  for (int i = rbeg + tid; i < rend; i += NT) {
    float4 yv = *reinterpret_cast<const float4*>(out + (size_t)i * 4);
    float4 qv = *reinterpret_cast<const float4*>(q + (size_t)i * 4);
    float a = qv.x, b = qv.y, c = qv.z, d = qv.w;
    float qn2 = __fmul_rn(a, a);
    qn2 = __fadd_rn(qn2, __fmul_rn(b, b));
    qn2 = __fadd_rn(qn2, __fmul_rn(c, c));
    qn2 = __fadd_rn(qn2, __fmul_rn(d, d));
    float qnr = sqrtf(qn2);
    a = __fdiv_rn(a, qnr); b = __fdiv_rn(b, qnr);
    c = __fdiv_rn(c, qnr); d = __fdiv_rn(d, qnr);
    float y0 = yv.x, y1 = yv.y, y2v = yv.z, y3 = yv.w;
    float o0v = __fadd_rn(__fadd_rn(__fadd_rn(__fmul_rn(a, y0), __fmul_rn(b, y1)),
                                    __fmul_rn(c, y2v)), __fmul_rn(d, y3));
    float o1v = __fadd_rn(__fadd_rn(__fadd_rn(__fmul_rn(-b, y0), __fmul_rn(a, y1)),
                                    __fmul_rn(-d, y2v)), __fmul_rn(c, y3));
    float o2v = __fadd_rn(__fadd_rn(__fadd_rn(__fmul_rn(-c, y0), __fmul_rn(d, y1)),
                                    __fmul_rn(a, y2v)), __fmul_rn(-b, y3));
    float o3v = __fadd_rn(__fadd_rn(__fadd_rn(__fmul_rn(d, y0), __fmul_rn(c, y1)),
                                    __fmul_rn(-b, y2v)), __fmul_rn(-a, y3));
    *reinterpret_cast<float4*>(out + (size_t)i * 4) =
        make_float4(o0v, o1v, o2v, o3v);
  }
}

extern "C" void kernel_launch(void* const* d_in, const int* in_sizes, int n_in,
                              void* d_out, int out_size, void* d_ws, size_t ws_size,
                              hipStream_t stream) {
  const float* q = (const float*)d_in[0];
  const float* Z = (const float*)d_in[1];
  const int* seed = (const int*)d_in[2];
  float* out = (float*)d_out;
  int N = in_sizes[0] / 4;

  int C = (N + GRID - 1) / GRID;  // rows per block (contiguous chunk)
  campose_kernel<<<GRID, NT, 0, stream>>>(q, Z, out, seed, N, C);
}

// Round 2
// 193.304 us; speedup vs baseline: 1.0823x; 1.0823x over previous
//
#include <hip/hip_runtime.h>
#include <cstdint>

// CamPoseNet: bit-faithful JAX threefry replication (validated rounds 1-4).
// Round 7: ILP forcing. R5/R6 counters showed per-iter VALU work is constant
// (~700 instrs) and single-wave issue efficiency is only ~24% -> the stall is
// serial dep chains (threefry add->rotl->xor), which the compiler did NOT
// interleave (VGPR=36). This round:
//  - trial5(): the 5 independent threefry-2x32 streams of one trial
//    (4 normal counters + 1 uniform counter) interleaved in array form.
//  - xla_erfinv4()/xla_logf_pos_k<K>(): the 4 erfinv polynomials (and the
//    2 final logs) interleaved the same way. Per-lane op sequences are
//    UNCHANGED (selects produce identical per-lane values) -> bit-exact.
//  - row-constant hoist: lam/sgi/sig (3 div + 3 sqrt + ~10 ops) computed
//    once per ROW (init/accept), not per trial.
//  - GRID back to 512 (best tail ratio); __launch_bounds__(256,2) so the
//    allocator has room for the interleaved live ranges.
// All float ops on the accept-decision path use __f*_rn intrinsics (no FMA
// contraction) - matches XLA:CPU strict mul/add. Do not alter any arithmetic.

#define DEVI __device__ __forceinline__
#define MAXT 96
#define GRID 512
#define NT 256

DEVI uint32_t rotl32(uint32_t v, int s) { return (v << s) | (v >> (32 - s)); }

// Threefry-2x32, 20 rounds (jax._src.prng.threefry2x32) - scalar form,
// used only by the chain producer.
DEVI void tf2x32(uint32_t k0, uint32_t k1, uint32_t x0, uint32_t x1,
                 uint32_t& o0, uint32_t& o1) {
  const uint32_t kx = k0 ^ k1 ^ 0x1BD11BDAu;
  x0 += k0; x1 += k1;
#define TFR(r) x0 += x1; x1 = rotl32(x1, (r)); x1 ^= x0;
  TFR(13) TFR(15) TFR(26) TFR(6)
  x0 += k1; x1 += kx + 1u;
  TFR(17) TFR(29) TFR(16) TFR(24)
  x0 += kx; x1 += k0 + 2u;
  TFR(13) TFR(15) TFR(26) TFR(6)
  x0 += k0; x1 += k1 + 3u;
  TFR(17) TFR(29) TFR(16) TFR(24)
  x0 += k1; x1 += kx + 4u;
  TFR(13) TFR(15) TFR(26) TFR(6)
  x0 += kx; x1 += k0 + 5u;
#undef TFR
  o0 = x0; o1 = x1;
}

// 5-way interleaved threefry: streams 0-3 use key (kA0,kA1) with counters
// base+j; stream 4 uses key (kB0,kB1) with counter ctr. Identical per-stream
// op sequence to tf2x32 (only instruction interleaving differs).
DEVI void tf_round5(uint32_t x0[5], uint32_t x1[5], int rr) {
#pragma unroll
  for (int j = 0; j < 5; ++j) {
    x0[j] += x1[j];
    x1[j] = rotl32(x1[j], rr);
    x1[j] ^= x0[j];
  }
}
DEVI void tf_inj5(uint32_t x0[5], uint32_t x1[5],
                  const uint32_t* sa, const uint32_t* sb, uint32_t add) {
#pragma unroll
  for (int j = 0; j < 5; ++j) { x0[j] += sa[j]; x1[j] += sb[j] + add; }
}

DEVI float u01_from_bits(uint32_t bits) {
  return __fsub_rn(__uint_as_float(0x3f800000u | (bits >> 9)), 1.0f);
}

DEVI void trial5(uint4 ck, uint32_t base, uint32_t ctr, float u[5]) {
  uint32_t s0[5], s1[5], s2k[5], x0[5], x1[5];
#pragma unroll
  for (int j = 0; j < 5; ++j) {
    uint32_t k0 = (j < 4) ? ck.x : ck.z;
    uint32_t k1 = (j < 4) ? ck.y : ck.w;
    s0[j] = k0; s1[j] = k1; s2k[j] = k0 ^ k1 ^ 0x1BD11BDAu;
    uint32_t c = (j < 4) ? (base + (uint32_t)j) : ctr;
    x0[j] = k0;        // 0 + k0
    x1[j] = c + k1;    // counter + k1
  }
  tf_round5(x0, x1, 13); tf_round5(x0, x1, 15);
  tf_round5(x0, x1, 26); tf_round5(x0, x1, 6);
  tf_inj5(x0, x1, s1, s2k, 1u);
  tf_round5(x0, x1, 17); tf_round5(x0, x1, 29);
  tf_round5(x0, x1, 16); tf_round5(x0, x1, 24);
  tf_inj5(x0, x1, s2k, s0, 2u);
  tf_round5(x0, x1, 13); tf_round5(x0, x1, 15);
  tf_round5(x0, x1, 26); tf_round5(x0, x1, 6);
  tf_inj5(x0, x1, s0, s1, 3u);
  tf_round5(x0, x1, 17); tf_round5(x0, x1, 29);
  tf_round5(x0, x1, 16); tf_round5(x0, x1, 24);
  tf_inj5(x0, x1, s1, s2k, 4u);
  tf_round5(x0, x1, 13); tf_round5(x0, x1, 15);
  tf_round5(x0, x1, 26); tf_round5(x0, x1, 6);
  tf_inj5(x0, x1, s2k, s0, 5u);
#pragma unroll
  for (int j = 0; j < 5; ++j) u[j] = u01_from_bits(x0[j] ^ x1[j]);
}

// K-way interleaved XLA:CPU Cephes-style f32 log, strict mul/add.
// Per-lane op sequence identical to the scalar version (selects pick the
// same values the branchy form computes). x > 0, normal.
template <int K>
DEVI void xla_logf_pos_k(const float* xf, float* out) {
  float e[K], m[K], z[K], y[K];
#pragma unroll
  for (int j = 0; j < K; ++j) {
    uint32_t bits = __float_as_uint(xf[j]);
    e[j] = (float)((int)(bits >> 23) - 126);
    m[j] = __uint_as_float((bits & 0x007fffffu) | 0x3f000000u);  // [0.5,1)
    bool mc = m[j] < 0.70710678118654752440f;
    float e_lo = __fsub_rn(e[j], 1.0f);
    float m_lo = __fadd_rn(__fsub_rn(m[j], 1.0f), m[j]);
    float m_hi = __fsub_rn(m[j], 1.0f);
    e[j] = mc ? e_lo : e[j];
    m[j] = mc ? m_lo : m_hi;
    z[j] = __fmul_rn(m[j], m[j]);
    y[j] = 7.0376836292e-2f;
  }
  const float LC[8] = {-1.1514610310e-1f,  1.1676998740e-1f,
                       -1.2420140846e-1f,  1.4249322787e-1f,
                       -1.6668057665e-1f,  2.0000714765e-1f,
                       -2.4999993993e-1f,  3.3333331174e-1f};
#pragma unroll
  for (int s = 0; s < 8; ++s)
#pragma unroll
    for (int j = 0; j < K; ++j)
      y[j] = __fadd_rn(__fmul_rn(y[j], m[j]), LC[s]);
#pragma unroll
  for (int j = 0; j < K; ++j) {
    float t = __fmul_rn(__fmul_rn(y[j], m[j]), z[j]);
    t = __fadd_rn(t, __fmul_rn(e[j], -2.12194440e-4f));
    t = __fsub_rn(t, __fmul_rn(z[j], 0.5f));
    float r = __fadd_rn(m[j], t);
    out[j] = __fadd_rn(r, __fmul_rn(e[j], 0.693359375f));
  }
}

// 4-way interleaved XLA ErfInv32 (coefficient-select form). Per-lane op
// sequence identical to the scalar select version -> bit-exact.
DEVI void xla_erfinv4(const float* xin, float* res) {
  float v[4], vp1[4], big[4], w[4], q[4], p[4];
  bool c[4];
#pragma unroll
  for (int j = 0; j < 4; ++j) {
    v[j] = -__fmul_rn(xin[j], xin[j]);
    vp1[j] = __fadd_rn(v[j], 1.0f);
  }
  xla_logf_pos_k<4>(vp1, big);
#pragma unroll
  for (int j = 0; j < 4; ++j) {
    float small = __fmul_rn(__fadd_rn(__fmul_rn(-0.5f, v[j]), 1.0f), v[j]);
    float l1p = (fabsf(v[j]) < 1e-4f) ? small : big[j];
    w[j] = -l1p;
    c[j] = (w[j] < 5.0f);
    float qc = __fsub_rn(w[j], 2.5f);
    float qr = __fsub_rn(sqrtf(w[j]), 3.0f);
    q[j] = c[j] ? qc : qr;
    p[j] = c[j] ? 2.81022636e-08f : -0.000200214257f;
  }
  const float CF[8] = { 3.43273939e-07f, -3.5233877e-06f, -4.39150654e-06f,
                        0.00021858087f,  -0.00125372503f, -0.00417768164f,
                        0.246640727f,     1.50140941f};
  const float CR[8] = { 0.000100950558f,  0.00134934322f, -0.00367342844f,
                        0.00573950773f,  -0.0076224613f,   0.00943887047f,
                        1.00167406f,      2.83297682f};
#pragma unroll
  for (int s = 0; s < 8; ++s)
#pragma unroll
    for (int j = 0; j < 4; ++j)
      p[j] = __fadd_rn(__fmul_rn(p[j], q[j]), c[j] ? CF[s] : CR[s]);
#pragma unroll
  for (int j = 0; j < 4; ++j) res[j] = __fmul_rn(p[j], xin[j]);
}

// ---------------------------------------------------------------------------
__global__ __launch_bounds__(256, 2) void campose_kernel(
    const float* __restrict__ q, const float* __restrict__ Z,
    float* __restrict__ out, const int* __restrict__ seedp, int N, int C) {
  __shared__ uint4 chain[MAXT + 1];
  __shared__ uint32_t next_row;
  __shared__ uint32_t wm;   // watermark: # of published chain entries

  const int tid = threadIdx.x;
  const int rbeg = blockIdx.x * C;
  const int rend = min(N, rbeg + C);
  if (tid == 0) { next_row = (uint32_t)(rbeg + 192); wm = 0u; }
  __syncthreads();

  const int wave = tid >> 6;
  if (wave == 0) {
    // Producer: lanes 0-2 of wave 0 walk the split() chain; publish each
    // entry with a release watermark. Other waves consume concurrently.
    int lane = tid & 63;
    uint32_t ka = 0u, kb = (uint32_t)seedp[0];
    uint32_t x1i = (lane == 2) ? 0u : (uint32_t)(lane + 1);
    for (int t = 0; t < MAXT; ++t) {
      uint32_t o0 = 0u, o1 = 0u;
      if (lane < 3) tf2x32(ka, kb, 0u, x1i, o0, o1);
      uint32_t s1a = __shfl(o0, 0, 64), s1b = __shfl(o1, 0, 64);
      uint32_t s2a = __shfl(o0, 1, 64), s2b = __shfl(o1, 1, 64);
      if (lane == 0) chain[t] = make_uint4(s1a, s1b, s2a, s2b);
      ka = __shfl(o0, 2, 64); kb = __shfl(o1, 2, 64);
      __threadfence_block();
      if (lane == 0) *(volatile uint32_t*)&wm = (uint32_t)(t + 1);
    }
    if (lane == 0) chain[MAXT] = make_uint4(0u, 0u, 0u, 0u);  // prefetch pad
    __threadfence_block();
    if (lane == 0) *(volatile uint32_t*)&wm = (uint32_t)(MAXT + 1);
  }

  const float sgi0 = __fadd_rn(1.0f, __fmul_rn(2.0f, 1e-6f));
  const float sig0 = sqrtf(__fdiv_rn(1.0f, sgi0));

  // --- per-lane row state: current row r + pre-grabbed next row rn ---
  int r, rn;
  if (wave == 0) {
    r  = (int)atomicAdd(&next_row, 1u);   // producer wave joins late; queue
    rn = (int)atomicAdd(&next_row, 1u);   // auto-balances
  } else {
    r  = rbeg + (tid - 64);               // static first 192 rows
    rn = (int)atomicAdd(&next_row, 1u);
  }
  bool have = (r < rend);
  float Zn0 = 0, Zn1 = 0, Zn2 = 0;
  // row constants (computed once per row, trial-invariant)
  float lam1 = 0, lam2 = 0, lam3 = 0;
  float sgi1 = 1, sgi2 = 1, sgi3 = 1;
  float sig1 = 1, sig2 = 1, sig3 = 1;
  if (have) {
    float Zc0 = Z[r * 3 + 0], Zc1 = Z[r * 3 + 1], Zc2 = Z[r * 3 + 2];
    lam1 = -Zc0; lam2 = -Zc1; lam3 = -Zc2;
    sgi1 = __fadd_rn(1.0f, __fmul_rn(2.0f, lam1));
    sgi2 = __fadd_rn(1.0f, __fmul_rn(2.0f, lam2));
    sgi3 = __fadd_rn(1.0f, __fmul_rn(2.0f, lam3));
    sig1 = sqrtf(__fdiv_rn(1.0f, sgi1));
    sig2 = sqrtf(__fdiv_rn(1.0f, sgi2));
    sig3 = sqrtf(__fdiv_rn(1.0f, sgi3));
  }
  if (rn < rend) { Zn0 = Z[rn * 3 + 0]; Zn1 = Z[rn * 3 + 1]; Zn2 = Z[rn * 3 + 2]; }

  // wait for chain[0]; cache it (reused at every accept)
  uint32_t wml = *(volatile uint32_t*)&wm;
  while (wml < 1u) wml = *(volatile uint32_t*)&wm;
  __threadfence_block();
  const uint4 ck0 = chain[0];
  uint4 ck = ck0;
  bool chain_all = (wml >= (uint32_t)(MAXT + 1));
  int t = 0;

  while (__ballot(have)) {
    if (have) {
      // prefetch next iteration's subkeys NOW (full iteration of slack)
      if (!chain_all) {
        uint32_t need = (uint32_t)(t + 2);
        uint32_t w_ = *(volatile uint32_t*)&wm;
        while (w_ < need) w_ = *(volatile uint32_t*)&wm;
        __threadfence_block();
        chain_all = (w_ >= (uint32_t)(MAXT + 1));
      }
      uint4 ckn = chain[t + 1];

      const uint32_t base = ((uint32_t)r) * 4u;

      // 5 interleaved threefry streams: 4 normals + 1 uniform
      float u5[5];
      trial5(ck, base, (uint32_t)r, u5);

      float xin[4];
#pragma unroll
      for (int j = 0; j < 4; ++j) {
        float x = __fadd_rn(__fmul_rn(u5[j], 2.0f), -0.99999994f);
        xin[j] = fmaxf(-0.99999994f, x);
      }
      float er[4];
      xla_erfinv4(xin, er);
      float uu = u5[4];

      float y0 = __fmul_rn(__fmul_rn(1.41421356237309504880f, er[0]), sig0);
      float y1 = __fmul_rn(__fmul_rn(1.41421356237309504880f, er[1]), sig1);
      float y2v = __fmul_rn(__fmul_rn(1.41421356237309504880f, er[2]), sig2);
      float y3 = __fmul_rn(__fmul_rn(1.41421356237309504880f, er[3]), sig3);

      // normalize (sequential reduce order)
      float n2 = __fmul_rn(y0, y0);
      n2 = __fadd_rn(n2, __fmul_rn(y1, y1));
      n2 = __fadd_rn(n2, __fmul_rn(y2v, y2v));
      n2 = __fadd_rn(n2, __fmul_rn(y3, y3));
      float nr = sqrtf(n2);
      y0 = __fdiv_rn(y0, nr); y1 = __fdiv_rn(y1, nr);
      y2v = __fdiv_rn(y2v, nr); y3 = __fdiv_rn(y3, nr);

      float s0q = __fmul_rn(y0, y0), s1q = __fmul_rn(y1, y1);
      float s2q = __fmul_rn(y2v, y2v), s3q = __fmul_rn(y3, y3);

      float s1v = __fmul_rn(s0q, 1e-6f);
      s1v = __fadd_rn(s1v, __fmul_rn(s1q, lam1));
      s1v = __fadd_rn(s1v, __fmul_rn(s2q, lam2));
      s1v = __fadd_rn(s1v, __fmul_rn(s3q, lam3));

      float s2v = __fmul_rn(s0q, sgi0);
      s2v = __fadd_rn(s2v, __fmul_rn(s1q, sgi1));
      s2v = __fadd_rn(s2v, __fmul_rn(s2q, sgi2));
      s2v = __fadd_rn(s2v, __fmul_rn(s3q, sgi3));

      // two independent logs, interleaved
      float lg_in[2] = {s2v, uu};
      float lg_out[2];
      xla_logf_pos_k<2>(lg_in, lg_out);

      float lr = __fsub_rn(-s1v, 2.7725887298583984f);  // 2*f32(ln 4)
      lr = __fadd_rn(lr, 1.5f);
      lr = __fadd_rn(lr, __fmul_rn(2.0f, lg_out[0]));

      float lu = (uu > 0.0f) ? lg_out[1] : -__builtin_inff();

      ++t;
      if ((lu < lr) || (t >= MAXT)) {
        // lean accept path: store y; E^T deferred to pass 2
        *reinterpret_cast<float4*>(out + (size_t)r * 4) =
            make_float4(y0, y1, y2v, y3);
        r = rn;
        // recompute row constants from prefetched Z (per row, cold path)
        lam1 = -Zn0; lam2 = -Zn1; lam3 = -Zn2;
        sgi1 = __fadd_rn(1.0f, __fmul_rn(2.0f, lam1));
        sgi2 = __fadd_rn(1.0f, __fmul_rn(2.0f, lam2));
        sgi3 = __fadd_rn(1.0f, __fmul_rn(2.0f, lam3));
        sig1 = sqrtf(__fdiv_rn(1.0f, sgi1));
        sig2 = sqrtf(__fdiv_rn(1.0f, sgi2));
        sig3 = sqrtf(__fdiv_rn(1.0f, sgi3));
        t = 0;
        ck = ck0;
        have = (r < rend);
        rn = (int)atomicAdd(&next_row, 1u);   // pre-grab: iterations of slack
        if (rn < rend) {
          Zn0 = Z[rn * 3 + 0]; Zn1 = Z[rn * 3 + 1]; Zn2 = Z[rn * 3 + 2];
        }
      } else {
        ck = ckn;
      }
    }
  }

  // --- pass 2: apply E^T over this block's chunk (coalesced) ---
  __syncthreads();   // all y-stores visible block-wide
  for (int i = rbeg + tid; i < rend; i += NT) {
    float4 yv = *reinterpret_cast<const float4*>(out + (size_t)i * 4);
    float4 qv = *reinterpret_cast<const float4*>(q + (size_t)i * 4);
    float a = qv.x, b = qv.y, c = qv.z, d = qv.w;
    float qn2 = __fmul_rn(a, a);
    qn2 = __fadd_rn(qn2, __fmul_rn(b, b));
    qn2 = __fadd_rn(qn2, __fmul_rn(c, c));
    qn2 = __fadd_rn(qn2, __fmul_rn(d, d));
    float qnr = sqrtf(qn2);
    a = __fdiv_rn(a, qnr); b = __fdiv_rn(b, qnr);
    c = __fdiv_rn(c, qnr); d = __fdiv_rn(d, qnr);
    float y0 = yv.x, y1 = yv.y, y2v = yv.z, y3 = yv.w;
    float o0v = __fadd_rn(__fadd_rn(__fadd_rn(__fmul_rn(a, y0), __fmul_rn(b, y1)),
                                    __fmul_rn(c, y2v)), __fmul_rn(d, y3));
    float o1v = __fadd_rn(__fadd_rn(__fadd_rn(__fmul_rn(-b, y0), __fmul_rn(a, y1)),
                                    __fmul_rn(-d, y2v)), __fmul_rn(c, y3));
    float o2v = __fadd_rn(__fadd_rn(__fadd_rn(__fmul_rn(-c, y0), __fmul_rn(d, y1)),
                                    __fmul_rn(a, y2v)), __fmul_rn(-b, y3));
    float o3v = __fadd_rn(__fadd_rn(__fadd_rn(__fmul_rn(d, y0), __fmul_rn(c, y1)),
                                    __fmul_rn(-b, y2v)), __fmul_rn(-a, y3));
    *reinterpret_cast<float4*>(out + (size_t)i * 4) =
        make_float4(o0v, o1v, o2v, o3v);
  }
}

extern "C" void kernel_launch(void* const* d_in, const int* in_sizes, int n_in,
                              void* d_out, int out_size, void* d_ws, size_t ws_size,
                              hipStream_t stream) {
  const float* q = (const float*)d_in[0];
  const float* Z = (const float*)d_in[1];
  const int* seed = (const int*)d_in[2];
  float* out = (float*)d_out;
  int N = in_sizes[0] / 4;

  int C = (N + GRID - 1) / GRID;  // rows per block (contiguous chunk)
  campose_kernel<<<GRID, NT, 0, stream>>>(q, Z, out, seed, N, C);
}

// Round 3
// 187.685 us; speedup vs baseline: 1.1147x; 1.0299x over previous
//
#include <hip/hip_runtime.h>
#include <cstdint>

// CamPoseNet: bit-faithful JAX threefry replication (validated rounds 1-4).
// Round 8: per-wave latency-hole elimination. R5-R7 cross-round data: VALUBusy
// pinned ~57% regardless of wave count; issued-work model consistent at ~650-700
// VALU instrs/iter -> 77us floor at 100% busy. More waves demonstrated net-loss
// (R6). This round fills the float-back-half holes:
//  - log(uu) merged into erfinv's 4-way log -> 5-way interleave (removes a
//    serial ~28-instr ILP=1 region from the end phase).
//  - row-constant LDS table: sgi/sig for all C rows precomputed in a dense
//    prepass; accepts read 6 floats from LDS instead of 3 div + 3 sqrt
//    sequences (executed ~every iter since P(any lane accepts)~1).
//  - end-phase keeps only log(s2v) serial (K=1).
// Per-value fp op DAGs are UNCHANGED (only scheduling/placement) -> bit-exact.
// All float ops on the accept-decision path use __f*_rn intrinsics (no FMA
// contraction) - matches XLA:CPU strict mul/add. Do not alter any arithmetic.

#define DEVI __device__ __forceinline__
#define MAXT 96
#define GRID 512
#define NT 256
#define CMAX 2048

DEVI uint32_t rotl32(uint32_t v, int s) { return (v << s) | (v >> (32 - s)); }

// Threefry-2x32, 20 rounds (jax._src.prng.threefry2x32) - scalar form,
// used only by the chain producer.
DEVI void tf2x32(uint32_t k0, uint32_t k1, uint32_t x0, uint32_t x1,
                 uint32_t& o0, uint32_t& o1) {
  const uint32_t kx = k0 ^ k1 ^ 0x1BD11BDAu;
  x0 += k0; x1 += k1;
#define TFR(r) x0 += x1; x1 = rotl32(x1, (r)); x1 ^= x0;
  TFR(13) TFR(15) TFR(26) TFR(6)
  x0 += k1; x1 += kx + 1u;
  TFR(17) TFR(29) TFR(16) TFR(24)
  x0 += kx; x1 += k0 + 2u;
  TFR(13) TFR(15) TFR(26) TFR(6)
  x0 += k0; x1 += k1 + 3u;
  TFR(17) TFR(29) TFR(16) TFR(24)
  x0 += k1; x1 += kx + 4u;
  TFR(13) TFR(15) TFR(26) TFR(6)
  x0 += kx; x1 += k0 + 5u;
#undef TFR
  o0 = x0; o1 = x1;
}

// 5-way interleaved threefry: streams 0-3 use key (ck.x,ck.y) with counters
// base+j; stream 4 uses key (ck.z,ck.w) with counter ctr. Identical per-stream
// op sequence to tf2x32 (only instruction interleaving differs).
DEVI void tf_round5(uint32_t x0[5], uint32_t x1[5], int rr) {
#pragma unroll
  for (int j = 0; j < 5; ++j) {
    x0[j] += x1[j];
    x1[j] = rotl32(x1[j], rr);
    x1[j] ^= x0[j];
  }
}
DEVI void tf_inj5(uint32_t x0[5], uint32_t x1[5],
                  const uint32_t* sa, const uint32_t* sb, uint32_t add) {
#pragma unroll
  for (int j = 0; j < 5; ++j) { x0[j] += sa[j]; x1[j] += sb[j] + add; }
}

DEVI float u01_from_bits(uint32_t bits) {
  return __fsub_rn(__uint_as_float(0x3f800000u | (bits >> 9)), 1.0f);
}

DEVI void trial5(uint4 ck, uint32_t base, uint32_t ctr, float u[5]) {
  uint32_t s0[5], s1[5], s2k[5], x0[5], x1[5];
#pragma unroll
  for (int j = 0; j < 5; ++j) {
    uint32_t k0 = (j < 4) ? ck.x : ck.z;
    uint32_t k1 = (j < 4) ? ck.y : ck.w;
    s0[j] = k0; s1[j] = k1; s2k[j] = k0 ^ k1 ^ 0x1BD11BDAu;
    uint32_t c = (j < 4) ? (base + (uint32_t)j) : ctr;
    x0[j] = k0;        // 0 + k0
    x1[j] = c + k1;    // counter + k1
  }
  tf_round5(x0, x1, 13); tf_round5(x0, x1, 15);
  tf_round5(x0, x1, 26); tf_round5(x0, x1, 6);
  tf_inj5(x0, x1, s1, s2k, 1u);
  tf_round5(x0, x1, 17); tf_round5(x0, x1, 29);
  tf_round5(x0, x1, 16); tf_round5(x0, x1, 24);
  tf_inj5(x0, x1, s2k, s0, 2u);
  tf_round5(x0, x1, 13); tf_round5(x0, x1, 15);
  tf_round5(x0, x1, 26); tf_round5(x0, x1, 6);
  tf_inj5(x0, x1, s0, s1, 3u);
  tf_round5(x0, x1, 17); tf_round5(x0, x1, 29);
  tf_round5(x0, x1, 16); tf_round5(x0, x1, 24);
  tf_inj5(x0, x1, s1, s2k, 4u);
  tf_round5(x0, x1, 13); tf_round5(x0, x1, 15);
  tf_round5(x0, x1, 26); tf_round5(x0, x1, 6);
  tf_inj5(x0, x1, s2k, s0, 5u);
#pragma unroll
  for (int j = 0; j < 5; ++j) u[j] = u01_from_bits(x0[j] ^ x1[j]);
}

// K-way interleaved XLA:CPU Cephes-style f32 log, strict mul/add.
// Per-lane op sequence identical to the scalar version (selects pick the
// same values the branchy form computes). x > 0, normal.
template <int K>
DEVI void xla_logf_pos_k(const float* xf, float* out) {
  float e[K], m[K], z[K], y[K];
#pragma unroll
  for (int j = 0; j < K; ++j) {
    uint32_t bits = __float_as_uint(xf[j]);
    e[j] = (float)((int)(bits >> 23) - 126);
    m[j] = __uint_as_float((bits & 0x007fffffu) | 0x3f000000u);  // [0.5,1)
    bool mc = m[j] < 0.70710678118654752440f;
    float e_lo = __fsub_rn(e[j], 1.0f);
    float m_lo = __fadd_rn(__fsub_rn(m[j], 1.0f), m[j]);
    float m_hi = __fsub_rn(m[j], 1.0f);
    e[j] = mc ? e_lo : e[j];
    m[j] = mc ? m_lo : m_hi;
    z[j] = __fmul_rn(m[j], m[j]);
    y[j] = 7.0376836292e-2f;
  }
  const float LC[8] = {-1.1514610310e-1f,  1.1676998740e-1f,
                       -1.2420140846e-1f,  1.4249322787e-1f,
                       -1.6668057665e-1f,  2.0000714765e-1f,
                       -2.4999993993e-1f,  3.3333331174e-1f};
#pragma unroll
  for (int s = 0; s < 8; ++s)
#pragma unroll
    for (int j = 0; j < K; ++j)
      y[j] = __fadd_rn(__fmul_rn(y[j], m[j]), LC[s]);
#pragma unroll
  for (int j = 0; j < K; ++j) {
    float t = __fmul_rn(__fmul_rn(y[j], m[j]), z[j]);
    t = __fadd_rn(t, __fmul_rn(e[j], -2.12194440e-4f));
    t = __fsub_rn(t, __fmul_rn(z[j], 0.5f));
    float r = __fadd_rn(m[j], t);
    out[j] = __fadd_rn(r, __fmul_rn(e[j], 0.693359375f));
  }
}

// 4-way interleaved XLA ErfInv32 + the uniform's log folded in as a 5th
// stream of the shared log (uu's log op-sequence identical to scalar form).
DEVI void xla_erfinv4_logu(const float* xin, float uu, float* res,
                           float& lg_uu) {
  float v[4], vp1[5], big[5], w[4], q[4], p[4];
  bool c[4];
#pragma unroll
  for (int j = 0; j < 4; ++j) {
    v[j] = -__fmul_rn(xin[j], xin[j]);
    vp1[j] = __fadd_rn(v[j], 1.0f);
  }
  vp1[4] = uu;                      // independent 5th log stream
  xla_logf_pos_k<5>(vp1, big);
  lg_uu = big[4];
#pragma unroll
  for (int j = 0; j < 4; ++j) {
    float small = __fmul_rn(__fadd_rn(__fmul_rn(-0.5f, v[j]), 1.0f), v[j]);
    float l1p = (fabsf(v[j]) < 1e-4f) ? small : big[j];
    w[j] = -l1p;
    c[j] = (w[j] < 5.0f);
    float qc = __fsub_rn(w[j], 2.5f);
    float qr = __fsub_rn(sqrtf(w[j]), 3.0f);
    q[j] = c[j] ? qc : qr;
    p[j] = c[j] ? 2.81022636e-08f : -0.000200214257f;
  }
  const float CF[8] = { 3.43273939e-07f, -3.5233877e-06f, -4.39150654e-06f,
                        0.00021858087f,  -0.00125372503f, -0.00417768164f,
                        0.246640727f,     1.50140941f};
  const float CR[8] = { 0.000100950558f,  0.00134934322f, -0.00367342844f,
                        0.00573950773f,  -0.0076224613f,   0.00943887047f,
                        1.00167406f,      2.83297682f};
#pragma unroll
  for (int s = 0; s < 8; ++s)
#pragma unroll
    for (int j = 0; j < 4; ++j)
      p[j] = __fadd_rn(__fmul_rn(p[j], q[j]), c[j] ? CF[s] : CR[s]);
#pragma unroll
  for (int j = 0; j < 4; ++j) res[j] = __fmul_rn(p[j], xin[j]);
}

// ---------------------------------------------------------------------------
__global__ __launch_bounds__(256, 2) void campose_kernel(
    const float* __restrict__ q, const float* __restrict__ Z,
    float* __restrict__ out, const int* __restrict__ seedp, int N, int C) {
  __shared__ uint4 chain[MAXT + 1];
  __shared__ float rowc[CMAX * 6];   // per-row sgi1..3, sig1..3 (bit-exact)
  __shared__ uint32_t next_row;
  __shared__ uint32_t wm;   // watermark: # of published chain entries

  const int tid = threadIdx.x;
  const int rbeg = blockIdx.x * C;
  const int rend = min(N, rbeg + C);
  const int crows = rend - rbeg;
  if (tid == 0) { next_row = (uint32_t)(rbeg + 192); wm = 0u; }

  // --- prepass: row constants (dense, high-ILP; values bit-identical to the
  // per-accept recompute they replace) ---
  for (int i = tid; i < crows; i += NT) {
    float z0 = Z[(size_t)(rbeg + i) * 3 + 0];
    float z1 = Z[(size_t)(rbeg + i) * 3 + 1];
    float z2 = Z[(size_t)(rbeg + i) * 3 + 2];
    float l1 = -z0, l2 = -z1, l3 = -z2;
    float g1 = __fadd_rn(1.0f, __fmul_rn(2.0f, l1));
    float g2 = __fadd_rn(1.0f, __fmul_rn(2.0f, l2));
    float g3 = __fadd_rn(1.0f, __fmul_rn(2.0f, l3));
    float s1_ = sqrtf(__fdiv_rn(1.0f, g1));
    float s2_ = sqrtf(__fdiv_rn(1.0f, g2));
    float s3_ = sqrtf(__fdiv_rn(1.0f, g3));
    rowc[i * 6 + 0] = g1; rowc[i * 6 + 1] = g2; rowc[i * 6 + 2] = g3;
    rowc[i * 6 + 3] = s1_; rowc[i * 6 + 4] = s2_; rowc[i * 6 + 5] = s3_;
  }
  __syncthreads();

  const int wave = tid >> 6;
  if (wave == 0) {
    // Producer: lanes 0-2 of wave 0 walk the split() chain; publish each
    // entry with a release watermark. Other waves consume concurrently.
    int lane = tid & 63;
    uint32_t ka = 0u, kb = (uint32_t)seedp[0];
    uint32_t x1i = (lane == 2) ? 0u : (uint32_t)(lane + 1);
    for (int t = 0; t < MAXT; ++t) {
      uint32_t o0 = 0u, o1 = 0u;
      if (lane < 3) tf2x32(ka, kb, 0u, x1i, o0, o1);
      uint32_t s1a = __shfl(o0, 0, 64), s1b = __shfl(o1, 0, 64);
      uint32_t s2a = __shfl(o0, 1, 64), s2b = __shfl(o1, 1, 64);
      if (lane == 0) chain[t] = make_uint4(s1a, s1b, s2a, s2b);
      ka = __shfl(o0, 2, 64); kb = __shfl(o1, 2, 64);
      __threadfence_block();
      if (lane == 0) *(volatile uint32_t*)&wm = (uint32_t)(t + 1);
    }
    if (lane == 0) chain[MAXT] = make_uint4(0u, 0u, 0u, 0u);  // prefetch pad
    __threadfence_block();
    if (lane == 0) *(volatile uint32_t*)&wm = (uint32_t)(MAXT + 1);
  }

  const float sgi0 = __fadd_rn(1.0f, __fmul_rn(2.0f, 1e-6f));
  const float sig0 = sqrtf(__fdiv_rn(1.0f, sgi0));

  // --- per-lane row state: current row r + pre-grabbed next row rn ---
  int r, rn;
  if (wave == 0) {
    r  = (int)atomicAdd(&next_row, 1u);   // producer wave joins late; queue
    rn = (int)atomicAdd(&next_row, 1u);   // auto-balances
  } else {
    r  = rbeg + (tid - 64);               // static first 192 rows
    rn = (int)atomicAdd(&next_row, 1u);
  }
  bool have = (r < rend);
  float Zn0 = 0, Zn1 = 0, Zn2 = 0;
  float lam1 = 0, lam2 = 0, lam3 = 0;
  float sgi1 = 1, sgi2 = 1, sgi3 = 1;
  float sig1 = 1, sig2 = 1, sig3 = 1;
  if (have) {
    lam1 = -Z[r * 3 + 0]; lam2 = -Z[r * 3 + 1]; lam3 = -Z[r * 3 + 2];
    int li = r - rbeg;
    sgi1 = rowc[li * 6 + 0]; sgi2 = rowc[li * 6 + 1]; sgi3 = rowc[li * 6 + 2];
    sig1 = rowc[li * 6 + 3]; sig2 = rowc[li * 6 + 4]; sig3 = rowc[li * 6 + 5];
  }
  if (rn < rend) { Zn0 = Z[rn * 3 + 0]; Zn1 = Z[rn * 3 + 1]; Zn2 = Z[rn * 3 + 2]; }

  // wait for chain[0]; cache it (reused at every accept)
  uint32_t wml = *(volatile uint32_t*)&wm;
  while (wml < 1u) wml = *(volatile uint32_t*)&wm;
  __threadfence_block();
  const uint4 ck0 = chain[0];
  uint4 ck = ck0;
  bool chain_all = (wml >= (uint32_t)(MAXT + 1));
  int t = 0;

  while (__ballot(have)) {
    if (have) {
      // prefetch next iteration's subkeys NOW (full iteration of slack)
      if (!chain_all) {
        uint32_t need = (uint32_t)(t + 2);
        uint32_t w_ = *(volatile uint32_t*)&wm;
        while (w_ < need) w_ = *(volatile uint32_t*)&wm;
        __threadfence_block();
        chain_all = (w_ >= (uint32_t)(MAXT + 1));
      }
      uint4 ckn = chain[t + 1];

      const uint32_t base = ((uint32_t)r) * 4u;

      // 5 interleaved threefry streams: 4 normals + 1 uniform
      float u5[5];
      trial5(ck, base, (uint32_t)r, u5);
      float uu = u5[4];

      float xin[4];
#pragma unroll
      for (int j = 0; j < 4; ++j) {
        float x = __fadd_rn(__fmul_rn(u5[j], 2.0f), -0.99999994f);
        xin[j] = fmaxf(-0.99999994f, x);
      }
      float er[4], lg_uu;
      xla_erfinv4_logu(xin, uu, er, lg_uu);   // log(uu) rides the 4-way log

      float y0 = __fmul_rn(__fmul_rn(1.41421356237309504880f, er[0]), sig0);
      float y1 = __fmul_rn(__fmul_rn(1.41421356237309504880f, er[1]), sig1);
      float y2v = __fmul_rn(__fmul_rn(1.41421356237309504880f, er[2]), sig2);
      float y3 = __fmul_rn(__fmul_rn(1.41421356237309504880f, er[3]), sig3);

      // normalize (sequential reduce order)
      float n2 = __fmul_rn(y0, y0);
      n2 = __fadd_rn(n2, __fmul_rn(y1, y1));
      n2 = __fadd_rn(n2, __fmul_rn(y2v, y2v));
      n2 = __fadd_rn(n2, __fmul_rn(y3, y3));
      float nr = sqrtf(n2);
      y0 = __fdiv_rn(y0, nr); y1 = __fdiv_rn(y1, nr);
      y2v = __fdiv_rn(y2v, nr); y3 = __fdiv_rn(y3, nr);

      float s0q = __fmul_rn(y0, y0), s1q = __fmul_rn(y1, y1);
      float s2q = __fmul_rn(y2v, y2v), s3q = __fmul_rn(y3, y3);

      float s1v = __fmul_rn(s0q, 1e-6f);
      s1v = __fadd_rn(s1v, __fmul_rn(s1q, lam1));
      s1v = __fadd_rn(s1v, __fmul_rn(s2q, lam2));
      s1v = __fadd_rn(s1v, __fmul_rn(s3q, lam3));

      float s2v = __fmul_rn(s0q, sgi0);
      s2v = __fadd_rn(s2v, __fmul_rn(s1q, sgi1));
      s2v = __fadd_rn(s2v, __fmul_rn(s2q, sgi2));
      s2v = __fadd_rn(s2v, __fmul_rn(s3q, sgi3));

      float lg_s2[1];
      xla_logf_pos_k<1>(&s2v, lg_s2);

      float lr = __fsub_rn(-s1v, 2.7725887298583984f);  // 2*f32(ln 4)
      lr = __fadd_rn(lr, 1.5f);
      lr = __fadd_rn(lr, __fmul_rn(2.0f, lg_s2[0]));

      float lu = (uu > 0.0f) ? lg_uu : -__builtin_inff();

      ++t;
      if ((lu < lr) || (t >= MAXT)) {
        // lean accept path: store y; E^T deferred to pass 2
        *reinterpret_cast<float4*>(out + (size_t)r * 4) =
            make_float4(y0, y1, y2v, y3);
        r = rn;
        lam1 = -Zn0; lam2 = -Zn1; lam3 = -Zn2;
        int li = (r < rend ? r : rend - 1) - rbeg;   // clamp: OOB lanes unused
        sgi1 = rowc[li * 6 + 0]; sgi2 = rowc[li * 6 + 1];
        sgi3 = rowc[li * 6 + 2];
        sig1 = rowc[li * 6 + 3]; sig2 = rowc[li * 6 + 4];
        sig3 = rowc[li * 6 + 5];
        t = 0;
        ck = ck0;
        have = (r < rend);
        rn = (int)atomicAdd(&next_row, 1u);   // pre-grab: iterations of slack
        if (rn < rend) {
          Zn0 = Z[rn * 3 + 0]; Zn1 = Z[rn * 3 + 1]; Zn2 = Z[rn * 3 + 2];
        }
      } else {
        ck = ckn;
      }
    }
  }

  // --- pass 2: apply E^T over this block's chunk (coalesced) ---
  __syncthreads();   // all y-stores visible block-wide
  for (int i = rbeg + tid; i < rend; i += NT) {
    float4 yv = *reinterpret_cast<const float4*>(out + (size_t)i * 4);
    float4 qv = *reinterpret_cast<const float4*>(q + (size_t)i * 4);
    float a = qv.x, b = qv.y, c = qv.z, d = qv.w;
    float qn2 = __fmul_rn(a, a);
    qn2 = __fadd_rn(qn2, __fmul_rn(b, b));
    qn2 = __fadd_rn(qn2, __fmul_rn(c, c));
    qn2 = __fadd_rn(qn2, __fmul_rn(d, d));
    float qnr = sqrtf(qn2);
    a = __fdiv_rn(a, qnr); b = __fdiv_rn(b, qnr);
    c = __fdiv_rn(c, qnr); d = __fdiv_rn(d, qnr);
    float y0 = yv.x, y1 = yv.y, y2v = yv.z, y3 = yv.w;
    float o0v = __fadd_rn(__fadd_rn(__fadd_rn(__fmul_rn(a, y0), __fmul_rn(b, y1)),
                                    __fmul_rn(c, y2v)), __fmul_rn(d, y3));
    float o1v = __fadd_rn(__fadd_rn(__fadd_rn(__fmul_rn(-b, y0), __fmul_rn(a, y1)),
                                    __fmul_rn(-d, y2v)), __fmul_rn(c, y3));
    float o2v = __fadd_rn(__fadd_rn(__fadd_rn(__fmul_rn(-c, y0), __fmul_rn(d, y1)),
                                    __fmul_rn(a, y2v)), __fmul_rn(-b, y3));
    float o3v = __fadd_rn(__fadd_rn(__fadd_rn(__fmul_rn(d, y0), __fmul_rn(c, y1)),
                                    __fmul_rn(-b, y2v)), __fmul_rn(-a, y3));
    *reinterpret_cast<float4*>(out + (size_t)i * 4) =
        make_float4(o0v, o1v, o2v, o3v);
  }
}

extern "C" void kernel_launch(void* const* d_in, const int* in_sizes, int n_in,
                              void* d_out, int out_size, void* d_ws, size_t ws_size,
                              hipStream_t stream) {
  const float* q = (const float*)d_in[0];
  const float* Z = (const float*)d_in[1];
  const int* seed = (const int*)d_in[2];
  float* out = (float*)d_out;
  int N = in_sizes[0] / 4;

  int nb = GRID;
  int C = (N + nb - 1) / nb;        // rows per block (contiguous chunk)
  if (C > CMAX) {                   // keep LDS row table in bounds
    nb = (N + CMAX - 1) / CMAX;
    C = (N + nb - 1) / nb;
  }
  campose_kernel<<<nb, NT, 0, stream>>>(q, Z, out, seed, N, C);
}

// Round 5
// 155.624 us; speedup vs baseline: 1.3443x; 1.2060x over previous
//
#include <hip/hip_runtime.h>
#include <cstdint>

// CamPoseNet: bit-faithful JAX threefry replication (validated rounds 1-4).
// Round 10: fixes R9's gang-tail row-loss bug (gang retired r but dropped the
// pre-grabbed rn and stopped draining the queue -> missing rows). Gang owners
// now do FULL row succession (r = rn; rn = atomicAdd), making the gang correct
// for any entry trigger. Further:
//  - rc[9][CMAX] LDS row constants now include lam1..3 (= -Z, computed in the
//    prepass, bit-exact): gang needs only (r,t) shuffles; normal accept path
//    drops its per-accept global Z prefetch entirely.
//  - gang geometry from acceptance model (p~0.16): 16 rows x 4 offsets/iter
//    retires ~8/iter vs A*0.16 normal -> trigger at popcount<=56 (any lane
//    death implies queue exhausted). Replaces ~24-iter masked drain w/ ~8-10.
//  - no runtime-indexed arrays in the gang (scratch hazard): per-lane
//    predicated bit-walk selects each group's source lane.
// Trial math (trial_eval) is byte-identical to the R8-validated sequence and
// is a pure function of (r, t, chain[t], row consts) -> bit-exact.
// All float ops on the accept-decision path use __f*_rn intrinsics (no FMA
// contraction) - matches XLA:CPU strict mul/add. Do not alter any arithmetic.

#define DEVI __device__ __forceinline__
#define MAXT 96
#define GRID 512
#define NT 256
#define CMAX 2048
#define GANGA 56
#define NG 16
#define GW 4

DEVI uint32_t rotl32(uint32_t v, int s) { return (v << s) | (v >> (32 - s)); }

// Threefry-2x32, 20 rounds (jax._src.prng.threefry2x32) - scalar form,
// used only by the chain producer.
DEVI void tf2x32(uint32_t k0, uint32_t k1, uint32_t x0, uint32_t x1,
                 uint32_t& o0, uint32_t& o1) {
  const uint32_t kx = k0 ^ k1 ^ 0x1BD11BDAu;
  x0 += k0; x1 += k1;
#define TFR(r) x0 += x1; x1 = rotl32(x1, (r)); x1 ^= x0;
  TFR(13) TFR(15) TFR(26) TFR(6)
  x0 += k1; x1 += kx + 1u;
  TFR(17) TFR(29) TFR(16) TFR(24)
  x0 += kx; x1 += k0 + 2u;
  TFR(13) TFR(15) TFR(26) TFR(6)
  x0 += k0; x1 += k1 + 3u;
  TFR(17) TFR(29) TFR(16) TFR(24)
  x0 += k1; x1 += kx + 4u;
  TFR(13) TFR(15) TFR(26) TFR(6)
  x0 += kx; x1 += k0 + 5u;
#undef TFR
  o0 = x0; o1 = x1;
}

// 5-way interleaved threefry: streams 0-3 use key (ck.x,ck.y) with counters
// base+j; stream 4 uses key (ck.z,ck.w) with counter ctr. Identical per-stream
// op sequence to tf2x32 (only instruction interleaving differs).
DEVI void tf_round5(uint32_t x0[5], uint32_t x1[5], int rr) {
#pragma unroll
  for (int j = 0; j < 5; ++j) {
    x0[j] += x1[j];
    x1[j] = rotl32(x1[j], rr);
    x1[j] ^= x0[j];
  }
}
DEVI void tf_inj5(uint32_t x0[5], uint32_t x1[5],
                  const uint32_t* sa, const uint32_t* sb, uint32_t add) {
#pragma unroll
  for (int j = 0; j < 5; ++j) { x0[j] += sa[j]; x1[j] += sb[j] + add; }
}

DEVI float u01_from_bits(uint32_t bits) {
  return __fsub_rn(__uint_as_float(0x3f800000u | (bits >> 9)), 1.0f);
}

DEVI void trial5(uint4 ck, uint32_t base, uint32_t ctr, float u[5]) {
  uint32_t s0[5], s1[5], s2k[5], x0[5], x1[5];
#pragma unroll
  for (int j = 0; j < 5; ++j) {
    uint32_t k0 = (j < 4) ? ck.x : ck.z;
    uint32_t k1 = (j < 4) ? ck.y : ck.w;
    s0[j] = k0; s1[j] = k1; s2k[j] = k0 ^ k1 ^ 0x1BD11BDAu;
    uint32_t c = (j < 4) ? (base + (uint32_t)j) : ctr;
    x0[j] = k0;        // 0 + k0
    x1[j] = c + k1;    // counter + k1
  }
  tf_round5(x0, x1, 13); tf_round5(x0, x1, 15);
  tf_round5(x0, x1, 26); tf_round5(x0, x1, 6);
  tf_inj5(x0, x1, s1, s2k, 1u);
  tf_round5(x0, x1, 17); tf_round5(x0, x1, 29);
  tf_round5(x0, x1, 16); tf_round5(x0, x1, 24);
  tf_inj5(x0, x1, s2k, s0, 2u);
  tf_round5(x0, x1, 13); tf_round5(x0, x1, 15);
  tf_round5(x0, x1, 26); tf_round5(x0, x1, 6);
  tf_inj5(x0, x1, s0, s1, 3u);
  tf_round5(x0, x1, 17); tf_round5(x0, x1, 29);
  tf_round5(x0, x1, 16); tf_round5(x0, x1, 24);
  tf_inj5(x0, x1, s1, s2k, 4u);
  tf_round5(x0, x1, 13); tf_round5(x0, x1, 15);
  tf_round5(x0, x1, 26); tf_round5(x0, x1, 6);
  tf_inj5(x0, x1, s2k, s0, 5u);
#pragma unroll
  for (int j = 0; j < 5; ++j) u[j] = u01_from_bits(x0[j] ^ x1[j]);
}

// K-way interleaved XLA:CPU Cephes-style f32 log, strict mul/add.
// Per-lane op sequence identical to the scalar version (selects pick the
// same values the branchy form computes). x > 0, normal.
template <int K>
DEVI void xla_logf_pos_k(const float* xf, float* out) {
  float e[K], m[K], z[K], y[K];
#pragma unroll
  for (int j = 0; j < K; ++j) {
    uint32_t bits = __float_as_uint(xf[j]);
    e[j] = (float)((int)(bits >> 23) - 126);
    m[j] = __uint_as_float((bits & 0x007fffffu) | 0x3f000000u);  // [0.5,1)
    bool mc = m[j] < 0.70710678118654752440f;
    float e_lo = __fsub_rn(e[j], 1.0f);
    float m_lo = __fadd_rn(__fsub_rn(m[j], 1.0f), m[j]);
    float m_hi = __fsub_rn(m[j], 1.0f);
    e[j] = mc ? e_lo : e[j];
    m[j] = mc ? m_lo : m_hi;
    z[j] = __fmul_rn(m[j], m[j]);
    y[j] = 7.0376836292e-2f;
  }
  const float LC[8] = {-1.1514610310e-1f,  1.1676998740e-1f,
                       -1.2420140846e-1f,  1.4249322787e-1f,
                       -1.6668057665e-1f,  2.0000714765e-1f,
                       -2.4999993993e-1f,  3.3333331174e-1f};
#pragma unroll
  for (int s = 0; s < 8; ++s)
#pragma unroll
    for (int j = 0; j < K; ++j)
      y[j] = __fadd_rn(__fmul_rn(y[j], m[j]), LC[s]);
#pragma unroll
  for (int j = 0; j < K; ++j) {
    float t = __fmul_rn(__fmul_rn(y[j], m[j]), z[j]);
    t = __fadd_rn(t, __fmul_rn(e[j], -2.12194440e-4f));
    t = __fsub_rn(t, __fmul_rn(z[j], 0.5f));
    float r = __fadd_rn(m[j], t);
    out[j] = __fadd_rn(r, __fmul_rn(e[j], 0.693359375f));
  }
}

// 4-way interleaved XLA ErfInv32 + the uniform's log folded in as a 5th
// stream of the shared log (uu's log op-sequence identical to scalar form).
DEVI void xla_erfinv4_logu(const float* xin, float uu, float* res,
                           float& lg_uu) {
  float v[4], vp1[5], big[5], w[4], q[4], p[4];
  bool c[4];
#pragma unroll
  for (int j = 0; j < 4; ++j) {
    v[j] = -__fmul_rn(xin[j], xin[j]);
    vp1[j] = __fadd_rn(v[j], 1.0f);
  }
  vp1[4] = uu;                      // independent 5th log stream
  xla_logf_pos_k<5>(vp1, big);
  lg_uu = big[4];
#pragma unroll
  for (int j = 0; j < 4; ++j) {
    float small = __fmul_rn(__fadd_rn(__fmul_rn(-0.5f, v[j]), 1.0f), v[j]);
    float l1p = (fabsf(v[j]) < 1e-4f) ? small : big[j];
    w[j] = -l1p;
    c[j] = (w[j] < 5.0f);
    float qc = __fsub_rn(w[j], 2.5f);
    float qr = __fsub_rn(sqrtf(w[j]), 3.0f);
    q[j] = c[j] ? qc : qr;
    p[j] = c[j] ? 2.81022636e-08f : -0.000200214257f;
  }
  const float CF[8] = { 3.43273939e-07f, -3.5233877e-06f, -4.39150654e-06f,
                        0.00021858087f,  -0.00125372503f, -0.00417768164f,
                        0.246640727f,     1.50140941f};
  const float CR[8] = { 0.000100950558f,  0.00134934322f, -0.00367342844f,
                        0.00573950773f,  -0.0076224613f,   0.00943887047f,
                        1.00167406f,      2.83297682f};
#pragma unroll
  for (int s = 0; s < 8; ++s)
#pragma unroll
    for (int j = 0; j < 4; ++j)
      p[j] = __fadd_rn(__fmul_rn(p[j], q[j]), c[j] ? CF[s] : CR[s]);
#pragma unroll
  for (int j = 0; j < 4; ++j) res[j] = __fmul_rn(p[j], xin[j]);
}

// One full rejection trial for row r with subkeys ck: pure function of
// (r, ck, row constants). Returns the lu<lr accept test; y out by ref.
// EXACT op sequence of the validated R8 loop body (shared by normal + gang
// paths -> bit-exact).
DEVI bool trial_eval(uint4 ck, int r,
                     float lam1, float lam2, float lam3,
                     float sgi1, float sgi2, float sgi3,
                     float sig1, float sig2, float sig3,
                     float sgi0, float sig0,
                     float& ry0, float& ry1, float& ry2, float& ry3) {
  const uint32_t base = ((uint32_t)r) * 4u;

  // 5 interleaved threefry streams: 4 normals + 1 uniform
  float u5[5];
  trial5(ck, base, (uint32_t)r, u5);
  float uu = u5[4];

  float xin[4];
#pragma unroll
  for (int j = 0; j < 4; ++j) {
    float x = __fadd_rn(__fmul_rn(u5[j], 2.0f), -0.99999994f);
    xin[j] = fmaxf(-0.99999994f, x);
  }
  float er[4], lg_uu;
  xla_erfinv4_logu(xin, uu, er, lg_uu);   // log(uu) rides the 4-way log

  float y0 = __fmul_rn(__fmul_rn(1.41421356237309504880f, er[0]), sig0);
  float y1 = __fmul_rn(__fmul_rn(1.41421356237309504880f, er[1]), sig1);
  float y2v = __fmul_rn(__fmul_rn(1.41421356237309504880f, er[2]), sig2);
  float y3 = __fmul_rn(__fmul_rn(1.41421356237309504880f, er[3]), sig3);

  // normalize (sequential reduce order)
  float n2 = __fmul_rn(y0, y0);
  n2 = __fadd_rn(n2, __fmul_rn(y1, y1));
  n2 = __fadd_rn(n2, __fmul_rn(y2v, y2v));
  n2 = __fadd_rn(n2, __fmul_rn(y3, y3));
  float nr = sqrtf(n2);
  y0 = __fdiv_rn(y0, nr); y1 = __fdiv_rn(y1, nr);
  y2v = __fdiv_rn(y2v, nr); y3 = __fdiv_rn(y3, nr);

  float s0q = __fmul_rn(y0, y0), s1q = __fmul_rn(y1, y1);
  float s2q = __fmul_rn(y2v, y2v), s3q = __fmul_rn(y3, y3);

  float s1v = __fmul_rn(s0q, 1e-6f);
  s1v = __fadd_rn(s1v, __fmul_rn(s1q, lam1));
  s1v = __fadd_rn(s1v, __fmul_rn(s2q, lam2));
  s1v = __fadd_rn(s1v, __fmul_rn(s3q, lam3));

  float s2v = __fmul_rn(s0q, sgi0);
  s2v = __fadd_rn(s2v, __fmul_rn(s1q, sgi1));
  s2v = __fadd_rn(s2v, __fmul_rn(s2q, sgi2));
  s2v = __fadd_rn(s2v, __fmul_rn(s3q, sgi3));

  float lg_s2[1];
  xla_logf_pos_k<1>(&s2v, lg_s2);

  float lr = __fsub_rn(-s1v, 2.7725887298583984f);  // 2*f32(ln 4)
  lr = __fadd_rn(lr, 1.5f);
  lr = __fadd_rn(lr, __fmul_rn(2.0f, lg_s2[0]));

  float lu = (uu > 0.0f) ? lg_uu : -__builtin_inff();

  ry0 = y0; ry1 = y1; ry2 = y2v; ry3 = y3;
  return (lu < lr);
}

// ---------------------------------------------------------------------------
__global__ __launch_bounds__(256, 2) void campose_kernel(
    const float* __restrict__ q, const float* __restrict__ Z,
    float* __restrict__ out, const int* __restrict__ seedp, int N, int C) {
  __shared__ uint4 chain[MAXT + 1];
  __shared__ float rc[9][CMAX];  // SoA: sgi1..3, sig1..3, lam1..3 (bit-exact)
  __shared__ uint32_t next_row;
  __shared__ uint32_t wm;   // watermark: # of published chain entries

  const int tid = threadIdx.x;
  const int lane = tid & 63;
  const int rbeg = blockIdx.x * C;
  const int rend = min(N, rbeg + C);
  const int crows = rend - rbeg;
  if (tid == 0) { next_row = (uint32_t)(rbeg + 192); wm = 0u; }

  // --- prepass: row constants (dense, high-ILP; values bit-identical to the
  // per-accept recompute they replace) ---
  for (int i = tid; i < crows; i += NT) {
    float z0 = Z[(size_t)(rbeg + i) * 3 + 0];
    float z1 = Z[(size_t)(rbeg + i) * 3 + 1];
    float z2 = Z[(size_t)(rbeg + i) * 3 + 2];
    float l1 = -z0, l2 = -z1, l3 = -z2;
    float g1 = __fadd_rn(1.0f, __fmul_rn(2.0f, l1));
    float g2 = __fadd_rn(1.0f, __fmul_rn(2.0f, l2));
    float g3 = __fadd_rn(1.0f, __fmul_rn(2.0f, l3));
    float s1_ = sqrtf(__fdiv_rn(1.0f, g1));
    float s2_ = sqrtf(__fdiv_rn(1.0f, g2));
    float s3_ = sqrtf(__fdiv_rn(1.0f, g3));
    rc[0][i] = g1; rc[1][i] = g2; rc[2][i] = g3;
    rc[3][i] = s1_; rc[4][i] = s2_; rc[5][i] = s3_;
    rc[6][i] = l1; rc[7][i] = l2; rc[8][i] = l3;
  }
  __syncthreads();

  const int wave = tid >> 6;
  if (wave == 0) {
    // Producer: lanes 0-2 of wave 0 walk the split() chain; publish each
    // entry with a release watermark. Other waves consume concurrently.
    uint32_t ka = 0u, kb = (uint32_t)seedp[0];
    uint32_t x1i = (lane == 2) ? 0u : (uint32_t)(lane + 1);
    for (int t = 0; t < MAXT; ++t) {
      uint32_t o0 = 0u, o1 = 0u;
      if (lane < 3) tf2x32(ka, kb, 0u, x1i, o0, o1);
      uint32_t s1a = __shfl(o0, 0, 64), s1b = __shfl(o1, 0, 64);
      uint32_t s2a = __shfl(o0, 1, 64), s2b = __shfl(o1, 1, 64);
      if (lane == 0) chain[t] = make_uint4(s1a, s1b, s2a, s2b);
      ka = __shfl(o0, 2, 64); kb = __shfl(o1, 2, 64);
      __threadfence_block();
      if (lane == 0) *(volatile uint32_t*)&wm = (uint32_t)(t + 1);
    }
    if (lane == 0) chain[MAXT] = make_uint4(0u, 0u, 0u, 0u);  // prefetch pad
    __threadfence_block();
    if (lane == 0) *(volatile uint32_t*)&wm = (uint32_t)(MAXT + 1);
  }

  const float sgi0 = __fadd_rn(1.0f, __fmul_rn(2.0f, 1e-6f));
  const float sig0 = sqrtf(__fdiv_rn(1.0f, sgi0));

  // --- per-lane row state: current row r + pre-grabbed next row rn ---
  int r, rn;
  if (wave == 0) {
    r  = (int)atomicAdd(&next_row, 1u);   // producer wave joins late; queue
    rn = (int)atomicAdd(&next_row, 1u);   // auto-balances
  } else {
    r  = rbeg + (tid - 64);               // static first 192 rows
    rn = (int)atomicAdd(&next_row, 1u);
  }
  bool have = (r < rend);
  float lam1 = 0, lam2 = 0, lam3 = 0;
  float sgi1 = 1, sgi2 = 1, sgi3 = 1;
  float sig1 = 1, sig2 = 1, sig3 = 1;
  if (have) {
    int li = r - rbeg;
    sgi1 = rc[0][li]; sgi2 = rc[1][li]; sgi3 = rc[2][li];
    sig1 = rc[3][li]; sig2 = rc[4][li]; sig3 = rc[5][li];
    lam1 = rc[6][li]; lam2 = rc[7][li]; lam3 = rc[8][li];
  }

  // wait for chain[0]; cache it (reused at every accept)
  uint32_t wml = *(volatile uint32_t*)&wm;
  while (wml < 1u) wml = *(volatile uint32_t*)&wm;
  __threadfence_block();
  const uint4 ck0 = chain[0];
  uint4 ck = ck0;
  int t = 0;

  // --- normal phase: per-lane async rows; leave when wave thins out.
  // Any lane death implies the queue counter passed rend, so popcount<64
  // means the queue is exhausted; gang mode (with full row succession) is
  // strictly better below A~50 (retire-rate model, p~0.16). ---
  while (true) {
    uint64_t msk = __ballot(have);
    if (__popcll(msk) <= GANGA) break;
    if (have) {
      // monotone watermark: re-poll only when the cache is insufficient
      if (wml < (uint32_t)(t + 2)) {
        uint32_t w_ = *(volatile uint32_t*)&wm;
        while (w_ < (uint32_t)(t + 2)) w_ = *(volatile uint32_t*)&wm;
        __threadfence_block();
        wml = w_;
      }
      uint4 ckn = chain[t + 1];

      float y0, y1, y2v, y3;
      bool alr = trial_eval(ck, r, lam1, lam2, lam3, sgi1, sgi2, sgi3,
                            sig1, sig2, sig3, sgi0, sig0, y0, y1, y2v, y3);

      ++t;
      if (alr || (t >= MAXT)) {
        // lean accept path: store y; E^T deferred to pass 2
        *reinterpret_cast<float4*>(out + (size_t)r * 4) =
            make_float4(y0, y1, y2v, y3);
        r = rn;
        int li = (r < rend ? r : rend - 1) - rbeg;   // clamp: OOB lanes unused
        sgi1 = rc[0][li]; sgi2 = rc[1][li]; sgi3 = rc[2][li];
        sig1 = rc[3][li]; sig2 = rc[4][li]; sig3 = rc[5][li];
        lam1 = rc[6][li]; lam2 = rc[7][li]; lam3 = rc[8][li];
        t = 0;
        ck = ck0;
        have = (r < rend);
        rn = (int)atomicAdd(&next_row, 1u);   // pre-grab: iterations of slack
      } else {
        ck = ckn;
      }
    }
  }

  // --- gang tail: NG rows x GW speculative offsets per wave-iteration.
  // Owners keep FULL row succession (r = rn; rn = atomicAdd) so held rn's
  // and any residual queue entries are consumed (R9 bug fix). ---
  uint64_t mask = __ballot(have);
  if (mask) {
    // chain must be fully published before direct chain[t] indexing
    if (wml < (uint32_t)(MAXT + 1)) {
      uint32_t w_ = *(volatile uint32_t*)&wm;
      while (w_ < (uint32_t)(MAXT + 1)) w_ = *(volatile uint32_t*)&wm;
      __threadfence_block();
      wml = w_;
    }
    while (mask) {
      int G = __popcll(mask); if (G > NG) G = NG;
      const int g = lane >> 2, k = lane & 3;
      const bool gact = (g < G);
      const int gidx = gact ? g : 0;
      // select the gidx-th set bit of mask (predicated walk; no arrays)
      uint64_t m = mask;
      int sl = __ffsll((unsigned long long)m) - 1;
#pragma unroll
      for (int i = 1; i < NG; ++i) {
        m &= m - 1;
        int b = __ffsll((unsigned long long)m) - 1;
        sl = (i <= gidx && b >= 0) ? b : sl;
      }
      int rg = __shfl(r, sl, 64);
      int tg = __shfl(t, sl, 64);
      int li = rg - rbeg;
      float G1 = rc[0][li], G2 = rc[1][li], G3 = rc[2][li];
      float S1 = rc[3][li], S2 = rc[4][li], S3 = rc[5][li];
      float L1 = rc[6][li], L2 = rc[7][li], L3 = rc[8][li];
      int ts = tg + k;                        // speculative trial index
      int tsc = ts < (MAXT - 1) ? ts : (MAXT - 1);
      uint4 cks = chain[tsc];
      float y0, y1, y2v, y3;
      bool alr = trial_eval(cks, rg, L1, L2, L3, G1, G2, G3,
                            S1, S2, S3, sgi0, sig0, y0, y1, y2v, y3);
      // forced accept at trial index MAXT-1 (sequential: post-inc t >= MAXT);
      // clamped lanes (ts > MAXT-1) can never win: an earlier forced k exists.
      // t += GW only happens when no accept in the window, so tg <= MAXT-1-GW
      // always holds on entry to the next window.
      bool acc = alr || (ts >= MAXT - 1);
      uint64_t bal = __ballot(acc && gact);
      uint64_t gb = (bal >> (g * GW)) & 0xfull;
      int kwin = gb ? (__ffsll((unsigned long long)gb) - 1) : GW;
      if (gact && k == kwin) {
        *reinterpret_cast<float4*>(out + (size_t)rg * 4) =
            make_float4(y0, y1, y2v, y3);
      }
      // owner bookkeeping with full succession (the R9 fix)
      int myidx = __popcll(mask & ((1ull << lane) - 1ull));
      if (have && myidx < G) {
        uint64_t gbb = (bal >> (myidx * GW)) & 0xfull;
        if (gbb) {
          r = rn;
          t = 0;
          have = (r < rend);
          rn = (int)atomicAdd(&next_row, 1u);
        } else {
          t += GW;                 // GW rejected trials consumed
        }
      }
      mask = __ballot(have);
    }
  }

  // --- pass 2: apply E^T over this block's chunk (coalesced) ---
  __syncthreads();   // all y-stores visible block-wide
  for (int i = rbeg + tid; i < rend; i += NT) {
    float4 yv = *reinterpret_cast<const float4*>(out + (size_t)i * 4);
    float4 qv = *reinterpret_cast<const float4*>(q + (size_t)i * 4);
    float a = qv.x, b = qv.y, c = qv.z, d = qv.w;
    float qn2 = __fmul_rn(a, a);
    qn2 = __fadd_rn(qn2, __fmul_rn(b, b));
    qn2 = __fadd_rn(qn2, __fmul_rn(c, c));
    qn2 = __fadd_rn(qn2, __fmul_rn(d, d));
    float qnr = sqrtf(qn2);
    a = __fdiv_rn(a, qnr); b = __fdiv_rn(b, qnr);
    c = __fdiv_rn(c, qnr); d = __fdiv_rn(d, qnr);
    float y0 = yv.x, y1 = yv.y, y2v = yv.z, y3 = yv.w;
    float o0v = __fadd_rn(__fadd_rn(__fadd_rn(__fmul_rn(a, y0), __fmul_rn(b, y1)),
                                    __fmul_rn(c, y2v)), __fmul_rn(d, y3));
    float o1v = __fadd_rn(__fadd_rn(__fadd_rn(__fmul_rn(-b, y0), __fmul_rn(a, y1)),
                                    __fmul_rn(-d, y2v)), __fmul_rn(c, y3));
    float o2v = __fadd_rn(__fadd_rn(__fadd_rn(__fmul_rn(-c, y0), __fmul_rn(d, y1)),
                                    __fmul_rn(a, y2v)), __fmul_rn(-b, y3));
    float o3v = __fadd_rn(__fadd_rn(__fadd_rn(__fmul_rn(d, y0), __fmul_rn(c, y1)),
                                    __fmul_rn(-b, y2v)), __fmul_rn(-a, y3));
    *reinterpret_cast<float4*>(out + (size_t)i * 4) =
        make_float4(o0v, o1v, o2v, o3v);
  }
}

extern "C" void kernel_launch(void* const* d_in, const int* in_sizes, int n_in,
                              void* d_out, int out_size, void* d_ws, size_t ws_size,
                              hipStream_t stream) {
  const float* q = (const float*)d_in[0];
  const float* Z = (const float*)d_in[1];
  const int* seed = (const int*)d_in[2];
  float* out = (float*)d_out;
  int N = in_sizes[0] / 4;

  int nb = GRID;
  int C = (N + nb - 1) / nb;        // rows per block (contiguous chunk)
  if (C > CMAX) {                   // keep LDS row table in bounds
    nb = (N + CMAX - 1) / CMAX;
    C = (N + nb - 1) / nb;
  }
  campose_kernel<<<nb, NT, 0, stream>>>(q, Z, out, seed, N, C);
}